// Round 1
// 10162.201 us; speedup vs baseline: 1.2299x; 1.2299x over previous
//
#include <hip/hip_runtime.h>

#define TT 512
#define BB 64
#define II 128
#define HH 1024
#define OO 128
#define NWG 196

typedef _Float16 half8 __attribute__((ext_vector_type(8)));
typedef float floatx4 __attribute__((ext_vector_type(4)));

__device__ __forceinline__ float sigm(float x){ return 1.0f/(1.0f + __expf(-x)); }

// ---------------- prep kernels ----------------
__global__ void prep_x_kernel(const float* __restrict__ x, _Float16* __restrict__ X16,
                              unsigned int* __restrict__ gcnt){
  int idx = blockIdx.x*256 + threadIdx.x;         // idx over [t][b][i]
  if (idx == 0) *gcnt = 0u;                       // zero the grid-barrier counter
  int i = idx & (II-1);
  int b = (idx >> 7) & (BB-1);
  int t = idx >> 13;
  X16[idx] = (_Float16)x[((size_t)b*TT + t)*II + i];
}

__global__ void prep_w_kernel(const float* __restrict__ wih1, const float* __restrict__ whh1,
                              const float* __restrict__ wih2, const float* __restrict__ whh2,
                              const float* __restrict__ wlin,
                              _Float16* __restrict__ W1, _Float16* __restrict__ W2,
                              _Float16* __restrict__ WL, _Float16* __restrict__ H1,
                              _Float16* __restrict__ H2){
  long idx = (long)blockIdx.x*256 + threadIdx.x;
  const long n1 = 4096L*1152, n2 = 4096L*2048, nl = 128L*1024;
  if (idx < n1){
    int k = (int)(idx % 1152); int j = (int)(idx / 1152);
    W1[idx] = (_Float16)(k < II ? wih1[(size_t)j*II + k] : whh1[(size_t)j*HH + (k-II)]);
  } else if ((idx -= n1) < n2){
    int k = (int)(idx % 2048); int j = (int)(idx / 2048);
    W2[idx] = (_Float16)(k < HH ? wih2[(size_t)j*HH + k] : whh2[(size_t)j*HH + (k-HH)]);
  } else if ((idx -= n2) < nl){
    WL[idx] = (_Float16)wlin[idx];
  } else {
    idx -= nl;                                    // [0, 2*BB*HH)
    H1[idx] = (_Float16)0.0f;
    H2[idx] = (_Float16)0.0f;
  }
}

// ---------------- device-scope grid barrier ----------------
// arrive: RELEASE fetch_add at agent scope (wbL2 -> LLC before counter bump).
// spin:   RELAXED agent load (sc1: reads the LLC coherence point; does NOT
//         invalidate L2 per poll, so LDS/L2-resident state stays warm).
// exit:   one ACQUIRE agent fence (invalidate L1/L2) then block barrier.
__device__ __forceinline__ void gbar(unsigned int* gcnt, unsigned int target){
  __syncthreads();                      // drains vmcnt: all block stores are in L2
  if (threadIdx.x == 0){
    __hip_atomic_fetch_add(gcnt, 1u, __ATOMIC_RELEASE, __HIP_MEMORY_SCOPE_AGENT);
    while (__hip_atomic_load(gcnt, __ATOMIC_RELAXED, __HIP_MEMORY_SCOPE_AGENT) < target)
      __builtin_amdgcn_s_sleep(1);
    __builtin_amdgcn_fence(__ATOMIC_ACQUIRE, "agent");
  }
  __syncthreads();
}

// ---------------- persistent pipelined kernel ----------------
// One resident WG per CU (196 <= 256 CUs, 147456B LDS, __launch_bounds__(256,1)).
// Same 3-stage pipeline as the dispatch-per-step version:
//   wg   0..63 : layer-1 step t=s      (16 cols x 4 gates, K=1152)
//   wg  64..191: layer-2 step t=s-1    ( 8 cols x 4 gates, K=2048)
//   wg 192..195: projection  t=s-2     (32 cols,           K=1024)
// Weights live in LDS (XOR-swizzled, conflict-free ds_read_b128); cell state
// lives in registers; H1/H2 parity slabs stay global (cross-WG traffic).
__global__ void __launch_bounds__(256, 1)
lstm_persist(const _Float16* __restrict__ X16,
             const _Float16* __restrict__ W1,
             const _Float16* __restrict__ W2,
             const _Float16* __restrict__ WL,
             _Float16* __restrict__ H1,
             _Float16* __restrict__ H2,
             const float* __restrict__ bi1, const float* __restrict__ bh1,
             const float* __restrict__ bi2, const float* __restrict__ bh2,
             const float* __restrict__ blin,
             float* __restrict__ out,
             unsigned int* __restrict__ gcnt)
{
  __shared__ _Float16 WS[73728];        // 147456 B (L1 slice is the largest)
  char* WSc = (char*)WS;
  const int wg   = blockIdx.x;
  const int tid  = threadIdx.x;
  const int wv   = tid >> 6;
  const int lane = tid & 63;
  const int q    = lane >> 4;
  const int n    = lane & 15;
  const int mrow = wv << 4;
  const int xr   = (n & 7) << 4;        // LDS XOR-swizzle key (byte bits 4..6)
  const floatx4 zero4 = {0.f, 0.f, 0.f, 0.f};

  if (wg < 64){
    // ================= layer 1 =================
    const int j0 = wg << 4;
    // stage weight slice: 64 rows (g*16+jl) x 1152 halves, swizzled
    for (int idx = tid; idx < 9216; idx += 256){
      int row = idx / 144, kc = idx - row*144;
      const _Float16* src = W1 + ((size_t)((row>>4)*HH + j0 + (row&15)))*1152 + kc*8;
      *(half8*)(WSc + row*2304 + ((kc*16) ^ ((row&7)<<4))) = *(const half8*)src;
    }
    __syncthreads();

    const int j = j0 + n;
    float bias[4];
    int wrowb[4];
#pragma unroll
    for (int g = 0; g < 4; ++g){
      bias[g]  = bi1[g*HH + j] + bh1[g*HH + j];
      wrowb[g] = (g*16 + n)*2304;
    }
    float c1r[4] = {0.f, 0.f, 0.f, 0.f};       // persistent cell state
    unsigned int target = 0;
#pragma unroll 1
    for (int s = 0; s < TT + 2; ++s){
      if (s < TT){
        const int t = s;
        const _Float16* xb = X16 + ((size_t)t*BB + (mrow+n))*II + q*8;
        const _Float16* hb = H1 + ((size_t)((t+1)&1)*BB + (mrow+n))*HH + q*8;
        half8 xf[4];
#pragma unroll
        for (int c = 0; c < 4; ++c) xf[c] = *(const half8*)(xb + c*32);
        half8 hA[32];
#pragma unroll
        for (int c = 0; c < 32; ++c) hA[c] = *(const half8*)(hb + c*32);

        floatx4 acc[4];
#pragma unroll
        for (int g = 0; g < 4; ++g) acc[g] = zero4;
#pragma unroll
        for (int c = 0; c < 4; ++c)
#pragma unroll
          for (int g = 0; g < 4; ++g){
            half8 w = *(const half8*)(WSc + wrowb[g] + ((q*16 + c*64) ^ xr));
            acc[g] = __builtin_amdgcn_mfma_f32_16x16x32_f16(xf[c], w, acc[g], 0, 0, 0);
          }
#pragma unroll
        for (int g = 0; g < 4; ++g)
#pragma unroll
          for (int c = 0; c < 32; ++c){
            half8 w = *(const half8*)(WSc + wrowb[g] + ((q*16 + (4+c)*64) ^ xr));
            acc[g] = __builtin_amdgcn_mfma_f32_16x16x32_f16(hA[c], w, acc[g], 0, 0, 0);
          }
        _Float16* ho = H1 + (size_t)(t&1)*BB*HH;
#pragma unroll
        for (int r = 0; r < 4; ++r){
          const int b = mrow + q*4 + r;
          float gi = acc[0][r] + bias[0];
          float gf = acc[1][r] + bias[1];
          float gg = acc[2][r] + bias[2];
          float go = acc[3][r] + bias[3];
          float cc = sigm(gf)*c1r[r] + sigm(gi)*tanhf(gg);
          c1r[r] = cc;
          float h = sigm(go)*tanhf(cc);
          ho[(size_t)b*HH + j] = (_Float16)h;
        }
      }
      target += NWG;
      gbar(gcnt, target);
    }
  } else if (wg < 192){
    // ================= layer 2 =================
    const int j0 = (wg - 64) << 3;
    // stage weight slice: 32 rows (gaterow*8+jl) x 2048 halves, swizzled
    for (int idx = tid; idx < 8192; idx += 256){
      int row = idx >> 8, kc = idx & 255;
      const _Float16* src = W2 + ((size_t)((row>>3)*HH + j0 + (row&7)))*2048 + kc*8;
      *(half8*)(WSc + row*4096 + ((kc*16) ^ ((row&7)<<4))) = *(const half8*)src;
    }
    __syncthreads();

    const int jj = j0 + (n & 7);
    float bias[4];
#pragma unroll
    for (int g = 0; g < 4; ++g) bias[g] = bi2[g*HH + jj] + bh2[g*HH + jj];
    const int rbase = (n < 8) ? 0 : 2;
    const int rowb0 = (((n>>3))*8 + (n&7))*4096;       // p=0 rows (gates i,f)
    const int rowb1 = ((2 + (n>>3))*8 + (n&7))*4096;   // p=1 rows (gates g,o)
    float c2r[2] = {0.f, 0.f};
    unsigned int target = 0;
#pragma unroll 1
    for (int s = 0; s < TT + 2; ++s){
      if (s >= 1 && s < TT + 1){
        const int t = s - 1;
        const _Float16* a1 = H1 + ((size_t)(t&1)*BB + (mrow+n))*HH + q*8;
        const _Float16* a2 = H2 + ((size_t)((t+1)&1)*BB + (mrow+n))*HH + q*8;
        half8 hA1[32];
#pragma unroll
        for (int c = 0; c < 32; ++c) hA1[c] = *(const half8*)(a1 + c*32);
        half8 hA2[32];
#pragma unroll
        for (int c = 0; c < 32; ++c) hA2[c] = *(const half8*)(a2 + c*32);

        floatx4 acc[2];
        acc[0] = zero4; acc[1] = zero4;
#pragma unroll
        for (int c = 0; c < 32; ++c){
          half8 w0 = *(const half8*)(WSc + rowb0 + ((q*16 + c*64) ^ xr));
          acc[0] = __builtin_amdgcn_mfma_f32_16x16x32_f16(hA1[c], w0, acc[0], 0, 0, 0);
          half8 w1 = *(const half8*)(WSc + rowb1 + ((q*16 + c*64) ^ xr));
          acc[1] = __builtin_amdgcn_mfma_f32_16x16x32_f16(hA1[c], w1, acc[1], 0, 0, 0);
        }
#pragma unroll
        for (int c = 0; c < 32; ++c){
          half8 w0 = *(const half8*)(WSc + rowb0 + ((q*16 + (32+c)*64) ^ xr));
          acc[0] = __builtin_amdgcn_mfma_f32_16x16x32_f16(hA2[c], w0, acc[0], 0, 0, 0);
          half8 w1 = *(const half8*)(WSc + rowb1 + ((q*16 + (32+c)*64) ^ xr));
          acc[1] = __builtin_amdgcn_mfma_f32_16x16x32_f16(hA2[c], w1, acc[1], 0, 0, 0);
        }
        // gather i,f,g,o per (b,jj): lanes n<8 hold (i,g), n>=8 hold (f,o)
        float vi[4], vf[4], vg[4], vo[4];
#pragma unroll
        for (int r = 0; r < 4; ++r){
          float p0 = acc[0][r], p1 = acc[1][r];
          float s0 = __shfl_xor(p0, 8, 64);
          float s1 = __shfl_xor(p1, 8, 64);
          vi[r] = (n < 8) ? p0 : s0;
          vf[r] = (n < 8) ? s0 : p0;
          vg[r] = (n < 8) ? p1 : s1;
          vo[r] = (n < 8) ? s1 : p1;
        }
        _Float16* ho = H2 + (size_t)(t&1)*BB*HH;
#pragma unroll
        for (int rr = 0; rr < 2; ++rr){
          int r = rbase + rr;
          const int b = mrow + q*4 + r;
          float gi = vi[r] + bias[0];
          float gf = vf[r] + bias[1];
          float gg = vg[r] + bias[2];
          float go = vo[r] + bias[3];
          float cc = sigm(gf)*c2r[rr] + sigm(gi)*tanhf(gg);
          c2r[rr] = cc;
          float h = sigm(go)*tanhf(cc);
          ho[(size_t)b*HH + jj] = (_Float16)h;
        }
      }
      target += NWG;
      gbar(gcnt, target);
    }
  } else {
    // ================= output projection =================
    const int j0 = (wg - 192) << 5;
    for (int idx = tid; idx < 4096; idx += 256){
      int row = idx >> 7, kc = idx & 127;
      const _Float16* src = WL + ((size_t)(j0 + row))*1024 + kc*8;
      *(half8*)(WSc + row*2048 + ((kc*16) ^ ((row&7)<<4))) = *(const half8*)src;
    }
    __syncthreads();

    float by[2];
    int rowb[2];
#pragma unroll
    for (int p = 0; p < 2; ++p){
      by[p]   = blin[j0 + p*16 + n];
      rowb[p] = (p*16 + n)*2048;
    }
    unsigned int target = 0;
#pragma unroll 1
    for (int s = 0; s < TT + 2; ++s){
      if (s >= 2){
        const int t = s - 2;
        const _Float16* a2 = H2 + ((size_t)(t&1)*BB + (mrow+n))*HH + q*8;
        half8 hA[32];
#pragma unroll
        for (int c = 0; c < 32; ++c) hA[c] = *(const half8*)(a2 + c*32);
        floatx4 acc[2];
        acc[0] = zero4; acc[1] = zero4;
#pragma unroll
        for (int p = 0; p < 2; ++p)
#pragma unroll
          for (int c = 0; c < 32; ++c){
            half8 w = *(const half8*)(WSc + rowb[p] + ((q*16 + c*64) ^ xr));
            acc[p] = __builtin_amdgcn_mfma_f32_16x16x32_f16(hA[c], w, acc[p], 0, 0, 0);
          }
#pragma unroll
        for (int p = 0; p < 2; ++p){
          int col = j0 + p*16 + n;
#pragma unroll
          for (int r = 0; r < 4; ++r){
            int b = mrow + q*4 + r;
            out[((size_t)b*TT + t)*OO + col] = acc[p][r] + by[p];
          }
        }
      }
      target += NWG;
      gbar(gcnt, target);
    }
  }
}

// ---------------- launch ----------------
extern "C" void kernel_launch(void* const* d_in, const int* in_sizes, int n_in,
                              void* d_out, int out_size, void* d_ws, size_t ws_size,
                              hipStream_t stream){
  const float* x    = (const float*)d_in[0];
  const float* wih1 = (const float*)d_in[1];
  const float* whh1 = (const float*)d_in[2];
  const float* bi1  = (const float*)d_in[3];
  const float* bh1  = (const float*)d_in[4];
  const float* wih2 = (const float*)d_in[5];
  const float* whh2 = (const float*)d_in[6];
  const float* bi2  = (const float*)d_in[7];
  const float* bh2  = (const float*)d_in[8];
  const float* wlin = (const float*)d_in[9];
  const float* blin = (const float*)d_in[10];
  float* out = (float*)d_out;

  char* ws = (char*)d_ws;
  _Float16* X16 = (_Float16*)(ws + 0);          //  8,388,608  [512][64][128]
  _Float16* W1  = (_Float16*)(ws + 8388608);    //  9,437,184  [4096][1152]
  _Float16* W2  = (_Float16*)(ws + 17825792);   // 16,777,216  [4096][2048]
  _Float16* WL  = (_Float16*)(ws + 34603008);   //    262,144  [128][1024]
  _Float16* H1  = (_Float16*)(ws + 34865152);   //    262,144  [2][64][1024]
  _Float16* H2  = (_Float16*)(ws + 35127296);   //    262,144  [2][64][1024]
  unsigned int* gcnt = (unsigned int*)(ws + 35389440);  // grid-barrier counter
  // total 35,389,444 bytes

  prep_x_kernel<<<dim3(16384), dim3(256), 0, stream>>>(x, X16, gcnt);
  prep_w_kernel<<<dim3(52224), dim3(256), 0, stream>>>(wih1, whh1, wih2, whh2, wlin,
                                                       W1, W2, WL, H1, H2);
  // single persistent dispatch: in-kernel grid barrier per pipeline interval
  lstm_persist<<<dim3(NWG), dim3(256), 0, stream>>>(
      X16, W1, W2, WL, H1, H2,
      bi1, bh1, bi2, bh2, blin, out, gcnt);
}

// Round 4
// 9711.417 us; speedup vs baseline: 1.2870x; 1.0464x over previous
//
#include <hip/hip_runtime.h>

#define TT 512
#define BB 64
#define II 128
#define HH 1024
#define OO 128
#define NWG 196
#define AGGWG 195

typedef _Float16 half8 __attribute__((ext_vector_type(8)));
typedef float floatx4 __attribute__((ext_vector_type(4)));
typedef unsigned long long u64;
typedef u64 u64x2 __attribute__((ext_vector_type(2)));

__device__ __forceinline__ float sigm(float x){ return 1.0f/(1.0f + __expf(-x)); }

// ---- cross-WG coherent loads: relaxed agent atomics (compiler-managed) ----
// Agent scope => LLC-coherent (sc bits emitted by the compiler's memory
// model); relaxed => no fences, no waitcnt baggage. Compiler owns dependency
// tracking and scheduling, so no hand vmcnt accounting (round-3 NaN bug).
__device__ __forceinline__ u64 ld_na(const u64* p){
  return __hip_atomic_load(p, __ATOMIC_RELAXED, __HIP_MEMORY_SCOPE_AGENT);
}
__device__ __forceinline__ half8 ld_frag(const _Float16* p){
  u64x2 t;
  t.x = ld_na((const u64*)p);
  t.y = ld_na(((const u64*)p) + 1);
  return __builtin_bit_cast(half8, t);
}
// cross-WG coherent store: write-through to LLC (bypass L1/L2).
__device__ __forceinline__ void st_sc(_Float16* p, _Float16 v){
  asm volatile("global_store_short %0, %1, off sc0 sc1" :: "v"(p), "v"(v) : "memory");
}

// ---------------- prep kernels ----------------
__global__ void prep_x_kernel(const float* __restrict__ x, _Float16* __restrict__ X16,
                              unsigned int* __restrict__ bar){
  int idx = blockIdx.x*256 + threadIdx.x;         // idx over [t][b][i]
  if (idx < 256) bar[idx] = 0u;                   // zero barrier slots + go flag
  int i = idx & (II-1);
  int b = (idx >> 7) & (BB-1);
  int t = idx >> 13;
  X16[idx] = (_Float16)x[((size_t)b*TT + t)*II + i];
}

__global__ void prep_w_kernel(const float* __restrict__ wih1, const float* __restrict__ whh1,
                              const float* __restrict__ wih2, const float* __restrict__ whh2,
                              const float* __restrict__ wlin,
                              _Float16* __restrict__ W1, _Float16* __restrict__ W2,
                              _Float16* __restrict__ WL, _Float16* __restrict__ H1,
                              _Float16* __restrict__ H2){
  long idx = (long)blockIdx.x*256 + threadIdx.x;
  const long n1 = 4096L*1152, n2 = 4096L*2048, nl = 128L*1024;
  if (idx < n1){
    int k = (int)(idx % 1152); int j = (int)(idx / 1152);
    W1[idx] = (_Float16)(k < II ? wih1[(size_t)j*II + k] : whh1[(size_t)j*HH + (k-II)]);
  } else if ((idx -= n1) < n2){
    int k = (int)(idx % 2048); int j = (int)(idx / 2048);
    W2[idx] = (_Float16)(k < HH ? wih2[(size_t)j*HH + k] : whh2[(size_t)j*HH + (k-HH)]);
  } else if ((idx -= n2) < nl){
    WL[idx] = (_Float16)wlin[idx];
  } else {
    idx -= nl;                                    // [0, 2*BB*HH)
    H1[idx] = (_Float16)0.0f;
    H2[idx] = (_Float16)0.0f;
  }
}

// ---------------- distributed epoch grid barrier (no contended RMW) ----------------
// arrive: each WG's thread0 stores epoch e into its OWN slot (parallel).
// aggregate: wave 0 of WG 195 polls all 196 slots (4 loads/lane), then
//            broadcasts go = e. spin: everyone polls go (read-only, backoff).
// Data visibility: all cross-WG stores are sc-bypass (at LLC once vmcnt
// retires, which the explicit waitcnt + __syncthreads guarantee before the
// slot store); readers use agent-scope loads (LLC-direct). Epochs are
// monotone so stale reads are always <= current: never passes early.
__device__ __forceinline__ void gbar(unsigned int* slots, unsigned int* go,
                                     int wg, int wv, int lane, unsigned int e){
  asm volatile("s_waitcnt vmcnt(0) lgkmcnt(0)" ::: "memory");
  __syncthreads();
  if (threadIdx.x == 0)
    __hip_atomic_store(&slots[wg], e, __ATOMIC_RELAXED, __HIP_MEMORY_SCOPE_AGENT);
  if (wg == AGGWG && wv == 0){
    for (;;){
      bool ok = true;
#pragma unroll
      for (int k = 0; k < 4; ++k){
        int s = lane + k*64;
        if (s < NWG)
          ok = ok && (__hip_atomic_load(&slots[s], __ATOMIC_RELAXED,
                                        __HIP_MEMORY_SCOPE_AGENT) >= e);
      }
      if (__all(ok)) break;
      __builtin_amdgcn_s_sleep(2);
    }
    if (lane == 0)
      __hip_atomic_store(go, e, __ATOMIC_RELAXED, __HIP_MEMORY_SCOPE_AGENT);
  }
  if (threadIdx.x == 0){
    while (__hip_atomic_load(go, __ATOMIC_RELAXED, __HIP_MEMORY_SCOPE_AGENT) < e)
      __builtin_amdgcn_s_sleep(8);
  }
  __syncthreads();
}

// ---------------- persistent pipelined kernel ----------------
//   wg   0..63 : layer-1 step t=s      (16 cols x 4 gates, K=1152)
//   wg  64..191: layer-2 step t=s-1    ( 8 cols x 4 gates, K=2048)
//   wg 192..195: projection  t=s-2     (32 cols,           K=1024)
// Weights in LDS (XOR-swizzled); cell state in registers; H1/H2 parity slabs
// in global via LLC-coherent ops (never cached in L1/L2 -> never stale).
__global__ void __launch_bounds__(256, 1)
lstm_persist(const _Float16* __restrict__ X16,
             const _Float16* __restrict__ W1,
             const _Float16* __restrict__ W2,
             const _Float16* __restrict__ WL,
             _Float16* __restrict__ H1,
             _Float16* __restrict__ H2,
             const float* __restrict__ bi1, const float* __restrict__ bh1,
             const float* __restrict__ bi2, const float* __restrict__ bh2,
             const float* __restrict__ blin,
             float* __restrict__ out,
             unsigned int* __restrict__ bar)
{
  __shared__ _Float16 WS[73728];        // 147456 B (L1 slice is the largest)
  char* WSc = (char*)WS;
  unsigned int* slots = bar;            // [0..195]
  unsigned int* go    = bar + 248;      // separate cache line
  const int wg   = blockIdx.x;
  const int tid  = threadIdx.x;
  const int wv   = tid >> 6;
  const int lane = tid & 63;
  const int q    = lane >> 4;
  const int n    = lane & 15;
  const int mrow = wv << 4;
  const int xr   = (n & 7) << 4;        // LDS XOR-swizzle key (byte bits 4..6)
  const floatx4 zero4 = {0.f, 0.f, 0.f, 0.f};

  if (wg < 64){
    // ================= layer 1 =================
    const int j0 = wg << 4;
    for (int idx = tid; idx < 9216; idx += 256){
      int row = idx / 144, kc = idx - row*144;
      const _Float16* src = W1 + ((size_t)((row>>4)*HH + j0 + (row&15)))*1152 + kc*8;
      *(half8*)(WSc + row*2304 + ((kc*16) ^ ((row&7)<<4))) = *(const half8*)src;
    }
    __syncthreads();

    const int j = j0 + n;
    float bias[4];
    int wrowb[4];
#pragma unroll
    for (int g = 0; g < 4; ++g){
      bias[g]  = bi1[g*HH + j] + bh1[g*HH + j];
      wrowb[g] = (g*16 + n)*2304;
    }
    float c1r[4] = {0.f, 0.f, 0.f, 0.f};
#pragma unroll 1
    for (int s = 0; s < TT + 2; ++s){
      if (s < TT){
        const int t = s;
        const _Float16* xb = X16 + ((size_t)t*BB + (mrow+n))*II + q*8;
        const _Float16* hb = H1 + ((size_t)((t+1)&1)*BB + (mrow+n))*HH + q*8;
        half8 hA[32];
#pragma unroll
        for (int c = 0; c < 32; ++c) hA[c] = ld_frag(hb + c*32);
        half8 xf[4];
#pragma unroll
        for (int c = 0; c < 4; ++c) xf[c] = *(const half8*)(xb + c*32);

        floatx4 acc[4];
#pragma unroll
        for (int g = 0; g < 4; ++g) acc[g] = zero4;
#pragma unroll
        for (int c = 0; c < 4; ++c)
#pragma unroll
          for (int g = 0; g < 4; ++g){
            half8 w = *(const half8*)(WSc + wrowb[g] + ((q*16 + c*64) ^ xr));
            acc[g] = __builtin_amdgcn_mfma_f32_16x16x32_f16(xf[c], w, acc[g], 0, 0, 0);
          }
#pragma unroll
        for (int g = 0; g < 4; ++g)
#pragma unroll
          for (int c = 0; c < 32; ++c){
            half8 w = *(const half8*)(WSc + wrowb[g] + ((q*16 + (4+c)*64) ^ xr));
            acc[g] = __builtin_amdgcn_mfma_f32_16x16x32_f16(hA[c], w, acc[g], 0, 0, 0);
          }
        _Float16* ho = H1 + (size_t)(t&1)*BB*HH;
#pragma unroll
        for (int r = 0; r < 4; ++r){
          const int b = mrow + q*4 + r;
          float gi = acc[0][r] + bias[0];
          float gf = acc[1][r] + bias[1];
          float gg = acc[2][r] + bias[2];
          float go_ = acc[3][r] + bias[3];
          float cc = sigm(gf)*c1r[r] + sigm(gi)*tanhf(gg);
          c1r[r] = cc;
          float h = sigm(go_)*tanhf(cc);
          st_sc(ho + (size_t)b*HH + j, (_Float16)h);
        }
      }
      gbar(slots, go, wg, wv, lane, (unsigned int)(s+1));
    }
  } else if (wg < 192){
    // ================= layer 2 =================
    const int j0 = (wg - 64) << 3;
    for (int idx = tid; idx < 8192; idx += 256){
      int row = idx >> 8, kc = idx & 255;
      const _Float16* src = W2 + ((size_t)((row>>3)*HH + j0 + (row&7)))*2048 + kc*8;
      *(half8*)(WSc + row*4096 + ((kc*16) ^ ((row&7)<<4))) = *(const half8*)src;
    }
    __syncthreads();

    const int jj = j0 + (n & 7);
    float bias[4];
#pragma unroll
    for (int g = 0; g < 4; ++g) bias[g] = bi2[g*HH + jj] + bh2[g*HH + jj];
    const int rbase = (n < 8) ? 0 : 2;
    const int rowb0 = (((n>>3))*8 + (n&7))*4096;       // p=0 rows (gates i,f)
    const int rowb1 = ((2 + (n>>3))*8 + (n&7))*4096;   // p=1 rows (gates g,o)
    float c2r[2] = {0.f, 0.f};
#pragma unroll 1
    for (int s = 0; s < TT + 2; ++s){
      if (s >= 1 && s < TT + 1){
        const int t = s - 1;
        const _Float16* a1 = H1 + ((size_t)(t&1)*BB + (mrow+n))*HH + q*8;
        const _Float16* a2 = H2 + ((size_t)((t+1)&1)*BB + (mrow+n))*HH + q*8;
        half8 hA1[32], hA2[32];
#pragma unroll
        for (int c = 0; c < 32; ++c) hA1[c] = ld_frag(a1 + c*32);
#pragma unroll
        for (int c = 0; c < 32; ++c) hA2[c] = ld_frag(a2 + c*32);

        floatx4 acc[2];
        acc[0] = zero4; acc[1] = zero4;
#pragma unroll
        for (int c = 0; c < 32; ++c){
          half8 w0 = *(const half8*)(WSc + rowb0 + ((q*16 + c*64) ^ xr));
          acc[0] = __builtin_amdgcn_mfma_f32_16x16x32_f16(hA1[c], w0, acc[0], 0, 0, 0);
          half8 w1 = *(const half8*)(WSc + rowb1 + ((q*16 + c*64) ^ xr));
          acc[1] = __builtin_amdgcn_mfma_f32_16x16x32_f16(hA1[c], w1, acc[1], 0, 0, 0);
        }
#pragma unroll
        for (int c = 0; c < 32; ++c){
          half8 w0 = *(const half8*)(WSc + rowb0 + ((q*16 + (32+c)*64) ^ xr));
          acc[0] = __builtin_amdgcn_mfma_f32_16x16x32_f16(hA2[c], w0, acc[0], 0, 0, 0);
          half8 w1 = *(const half8*)(WSc + rowb1 + ((q*16 + (32+c)*64) ^ xr));
          acc[1] = __builtin_amdgcn_mfma_f32_16x16x32_f16(hA2[c], w1, acc[1], 0, 0, 0);
        }
        // gather i,f,g,o per (b,jj): lanes n<8 hold (i,g), n>=8 hold (f,o)
        float vi[4], vf[4], vg[4], vo[4];
#pragma unroll
        for (int r = 0; r < 4; ++r){
          float p0 = acc[0][r], p1 = acc[1][r];
          float s0 = __shfl_xor(p0, 8, 64);
          float s1 = __shfl_xor(p1, 8, 64);
          vi[r] = (n < 8) ? p0 : s0;
          vf[r] = (n < 8) ? s0 : p0;
          vg[r] = (n < 8) ? p1 : s1;
          vo[r] = (n < 8) ? s1 : p1;
        }
        _Float16* ho = H2 + (size_t)(t&1)*BB*HH;
#pragma unroll
        for (int rr = 0; rr < 2; ++rr){
          int r = rbase + rr;
          const int b = mrow + q*4 + r;
          float gi = vi[r] + bias[0];
          float gf = vf[r] + bias[1];
          float gg = vg[r] + bias[2];
          float go_ = vo[r] + bias[3];
          float cc = sigm(gf)*c2r[rr] + sigm(gi)*tanhf(gg);
          c2r[rr] = cc;
          float h = sigm(go_)*tanhf(cc);
          st_sc(ho + (size_t)b*HH + jj, (_Float16)h);
        }
      }
      gbar(slots, go, wg, wv, lane, (unsigned int)(s+1));
    }
  } else {
    // ================= output projection =================
    const int j0 = (wg - 192) << 5;
    for (int idx = tid; idx < 4096; idx += 256){
      int row = idx >> 7, kc = idx & 127;
      const _Float16* src = WL + ((size_t)(j0 + row))*1024 + kc*8;
      *(half8*)(WSc + row*2048 + ((kc*16) ^ ((row&7)<<4))) = *(const half8*)src;
    }
    __syncthreads();

    float by[2];
    int rowb[2];
#pragma unroll
    for (int p = 0; p < 2; ++p){
      by[p]   = blin[j0 + p*16 + n];
      rowb[p] = (p*16 + n)*2048;
    }
#pragma unroll 1
    for (int s = 0; s < TT + 2; ++s){
      if (s >= 2){
        const int t = s - 2;
        const _Float16* a2 = H2 + ((size_t)(t&1)*BB + (mrow+n))*HH + q*8;
        half8 hA[32];
#pragma unroll
        for (int c = 0; c < 32; ++c) hA[c] = ld_frag(a2 + c*32);
        floatx4 acc[2];
        acc[0] = zero4; acc[1] = zero4;
#pragma unroll
        for (int p = 0; p < 2; ++p)
#pragma unroll
          for (int c = 0; c < 32; ++c){
            half8 w = *(const half8*)(WSc + rowb[p] + ((q*16 + c*64) ^ xr));
            acc[p] = __builtin_amdgcn_mfma_f32_16x16x32_f16(hA[c], w, acc[p], 0, 0, 0);
          }
#pragma unroll
        for (int p = 0; p < 2; ++p){
          int col = j0 + p*16 + n;
#pragma unroll
          for (int r = 0; r < 4; ++r){
            int b = mrow + q*4 + r;
            out[((size_t)b*TT + t)*OO + col] = acc[p][r] + by[p];
          }
        }
      }
      gbar(slots, go, wg, wv, lane, (unsigned int)(s+1));
    }
  }
}

// ---------------- launch ----------------
extern "C" void kernel_launch(void* const* d_in, const int* in_sizes, int n_in,
                              void* d_out, int out_size, void* d_ws, size_t ws_size,
                              hipStream_t stream){
  const float* x    = (const float*)d_in[0];
  const float* wih1 = (const float*)d_in[1];
  const float* whh1 = (const float*)d_in[2];
  const float* bi1  = (const float*)d_in[3];
  const float* bh1  = (const float*)d_in[4];
  const float* wih2 = (const float*)d_in[5];
  const float* whh2 = (const float*)d_in[6];
  const float* bi2  = (const float*)d_in[7];
  const float* bh2  = (const float*)d_in[8];
  const float* wlin = (const float*)d_in[9];
  const float* blin = (const float*)d_in[10];
  float* out = (float*)d_out;

  char* ws = (char*)d_ws;
  _Float16* X16 = (_Float16*)(ws + 0);          //  8,388,608  [512][64][128]
  _Float16* W1  = (_Float16*)(ws + 8388608);    //  9,437,184  [4096][1152]
  _Float16* W2  = (_Float16*)(ws + 17825792);   // 16,777,216  [4096][2048]
  _Float16* WL  = (_Float16*)(ws + 34603008);   //    262,144  [128][1024]
  _Float16* H1  = (_Float16*)(ws + 34865152);   //    262,144  [2][64][1024]
  _Float16* H2  = (_Float16*)(ws + 35127296);   //    262,144  [2][64][1024]
  unsigned int* bar = (unsigned int*)(ws + 35389440);  // 1024 B barrier area
  // total 35,390,464 bytes

  prep_x_kernel<<<dim3(16384), dim3(256), 0, stream>>>(x, X16, bar);
  prep_w_kernel<<<dim3(52224), dim3(256), 0, stream>>>(wih1, whh1, wih2, whh2, wlin,
                                                       W1, W2, WL, H1, H2);
  lstm_persist<<<dim3(NWG), dim3(256), 0, stream>>>(
      X16, W1, W2, WL, H1, H2,
      bi1, bh1, bi2, bh2, blin, out, bar);
}

// Round 5
// 6864.917 us; speedup vs baseline: 1.8207x; 1.4146x over previous
//
#include <hip/hip_runtime.h>

#define TT 512
#define BB 64
#define II 128
#define HH 1024
#define OO 128
#define NWG 196

typedef _Float16 half8 __attribute__((ext_vector_type(8)));
typedef float floatx4 __attribute__((ext_vector_type(4)));

__device__ __forceinline__ float sigm(float x){ return 1.0f/(1.0f + __expf(-x)); }

// ---- LLC-coherent 16B loads (L1/L2-bypass), batch-issued, NO internal wait.
// Caller must drain with vmcnt(0) + sched_barrier before consuming.
template<int C, int N, int STRIDE>
struct LdSC {
  static __device__ __forceinline__ void go(half8* d, const _Float16* b){
    asm volatile("global_load_dwordx4 %0, %1, off offset:%2 sc0 sc1"
                 : "=v"(d[C]) : "v"(b), "n"(C*STRIDE));
    LdSC<C+1, N, STRIDE>::go(d, b);
  }
};
template<int N, int STRIDE>
struct LdSC<N, N, STRIDE> {
  static __device__ __forceinline__ void go(half8*, const _Float16*){}
};

// write-through-to-LLC store (visible once vmcnt retires)
__device__ __forceinline__ void st_sc(_Float16* p, _Float16 v){
  asm volatile("global_store_short %0, %1, off sc0 sc1" :: "v"(p), "v"(v) : "memory");
}

#define VDRAIN do { asm volatile("s_waitcnt vmcnt(0)" ::: "memory"); \
                    __builtin_amdgcn_sched_barrier(0); } while(0)

// ---- per-wave epoch flag wait: all F1>=a, all F2>=b, all FP>=c (skip if <=0)
__device__ __forceinline__ void wait_flags(unsigned int* F1, unsigned int* F2,
                                           unsigned int* FP,
                                           int a, int b, int c, int lane){
  for (;;){
    bool ok = true;
    if (a > 0){
#pragma unroll
      for (int k = 0; k < 4; ++k)
        ok &= (int)__hip_atomic_load(&F1[lane + k*64], __ATOMIC_RELAXED,
                                     __HIP_MEMORY_SCOPE_AGENT) >= a;
    }
    if (b > 0){
#pragma unroll
      for (int k = 0; k < 8; ++k)
        ok &= (int)__hip_atomic_load(&F2[lane + k*64], __ATOMIC_RELAXED,
                                     __HIP_MEMORY_SCOPE_AGENT) >= b;
    }
    if (c > 0){
      ok &= (int)__hip_atomic_load(&FP[lane & 15], __ATOMIC_RELAXED,
                                   __HIP_MEMORY_SCOPE_AGENT) >= c;
    }
    if (__all(ok)) break;
    __builtin_amdgcn_s_sleep(1);
  }
}

// ---------------- prep kernels ----------------
__global__ void prep_x_kernel(const float* __restrict__ x, _Float16* __restrict__ X16,
                              unsigned int* __restrict__ bar){
  int idx = blockIdx.x*256 + threadIdx.x;         // idx over [t][b][i]
  if (idx < 1024) bar[idx] = 0u;                  // zero all flag slots
  int i = idx & (II-1);
  int b = (idx >> 7) & (BB-1);
  int t = idx >> 13;
  X16[idx] = (_Float16)x[((size_t)b*TT + t)*II + i];
}

__global__ void prep_w_kernel(const float* __restrict__ wih1, const float* __restrict__ whh1,
                              const float* __restrict__ wih2, const float* __restrict__ whh2,
                              const float* __restrict__ wlin,
                              _Float16* __restrict__ W1, _Float16* __restrict__ W2,
                              _Float16* __restrict__ WL, _Float16* __restrict__ H1,
                              _Float16* __restrict__ H2){
  long idx = (long)blockIdx.x*256 + threadIdx.x;
  const long n1 = 4096L*1152, n2 = 4096L*2048, nl = 128L*1024;
  if (idx < n1){
    int k = (int)(idx % 1152); int j = (int)(idx / 1152);
    W1[idx] = (_Float16)(k < II ? wih1[(size_t)j*II + k] : whh1[(size_t)j*HH + (k-II)]);
  } else if ((idx -= n1) < n2){
    int k = (int)(idx % 2048); int j = (int)(idx / 2048);
    W2[idx] = (_Float16)(k < HH ? wih2[(size_t)j*HH + k] : whh2[(size_t)j*HH + (k-HH)]);
  } else if ((idx -= n2) < nl){
    WL[idx] = (_Float16)wlin[idx];
  } else {
    idx -= nl;                                    // [0, 3*BB*HH): zero 3 slots
    H1[idx] = (_Float16)0.0f;
    H2[idx] = (_Float16)0.0f;
  }
}

// ---------------- persistent dataflow kernel ----------------
// 196 WGs x 512 threads (8 waves = 4 mrow-groups x 2 K-halves).
//   wg   0..63 : layer-1, 16 cols x 4 gates, K=1152 split {x+h[0:512] | h[512:1024]}
//   wg  64..191: layer-2,  8 cols x 4 gates, K=2048 split {h1(t) | h2(t-1)}
//   wg 192..195: projection, 32 cols, K=1024 split {[0:512] | [512:1024]}
// No global barrier: per-wave monotone epoch flags (F1/F2/FP, value=step+1) on
// 3-slot rotating H buffers. K-halves reduced intra-WG through LDS.
__global__ void __launch_bounds__(512, 2)
lstm_persist(const _Float16* __restrict__ X16,
             const _Float16* __restrict__ W1,
             const _Float16* __restrict__ W2,
             const _Float16* __restrict__ WL,
             _Float16* __restrict__ H1,
             _Float16* __restrict__ H2,
             const float* __restrict__ bi1, const float* __restrict__ bh1,
             const float* __restrict__ bi2, const float* __restrict__ bh2,
             const float* __restrict__ blin,
             float* __restrict__ out,
             unsigned int* __restrict__ bar)
{
  __shared__ _Float16 WS[73728];        // 147456 B weight slice (XOR-swizzled)
  __shared__ floatx4 RBv[512];          // 8192 B K-half reduction buffer
  char* WSc = (char*)WS;
  unsigned int* F1 = bar;               // [256] layer-1 per-wave flags
  unsigned int* F2 = bar + 256;         // [512] layer-2 per-wave flags
  unsigned int* FP = bar + 768;         // [16]  projection per-wave flags
  const int wg   = blockIdx.x;
  const int tid  = threadIdx.x;
  const int wv   = tid >> 6;            // 0..7
  const int mg   = wv & 3;              // mrow group
  const int kh   = wv >> 2;             // K-half
  const int lane = tid & 63;
  const int q    = lane >> 4;
  const int n    = lane & 15;
  const int mrow = mg << 4;
  const int xr   = (n & 7) << 4;        // LDS XOR-swizzle key
  const int ri   = (mg*64 + lane)*2;    // reduction slot
  const floatx4 zero4 = {0.f, 0.f, 0.f, 0.f};

  if (wg < 64){
    // ================= layer 1 =================
    const int j0 = wg << 4;
    for (int idx = tid; idx < 9216; idx += 512){
      int row = idx / 144, kc = idx - row*144;
      const _Float16* src = W1 + ((size_t)((row>>4)*HH + j0 + (row&15)))*1152 + kc*8;
      *(half8*)(WSc + row*2304 + ((kc*16) ^ ((row&7)<<4))) = *(const half8*)src;
    }
    __syncthreads();

    const int j = j0 + n;
    float bias[4];
    int wrowb[4];
#pragma unroll
    for (int g = 0; g < 4; ++g){
      bias[g]  = bi1[g*HH + j] + bh1[g*HH + j];
      wrowb[g] = (g*16 + n)*2304;
    }
    float c1r[4] = {0.f, 0.f, 0.f, 0.f};
    int cur = 0, prv = 2;
#pragma unroll 1
    for (int t = 0; t < TT; ++t){
      floatx4 acc[4];
#pragma unroll
      for (int g = 0; g < 4; ++g) acc[g] = zero4;
      if (kh == 0){
        // x-part overlaps the flag wait
        const _Float16* xb = X16 + ((size_t)t*BB + (mrow+n))*II + q*8;
        half8 xf[4];
#pragma unroll
        for (int c = 0; c < 4; ++c) xf[c] = *(const half8*)(xb + c*32);
#pragma unroll
        for (int c = 0; c < 4; ++c)
#pragma unroll
          for (int g = 0; g < 4; ++g){
            half8 w = *(const half8*)(WSc + wrowb[g] + ((q*16 + c*64) ^ xr));
            acc[g] = __builtin_amdgcn_mfma_f32_16x16x32_f16(xf[c], w, acc[g], 0, 0, 0);
          }
        wait_flags(F1, F2, FP, t, t-2, 0, lane);   // h1(t-1) ready; slot safe
        const _Float16* hb = H1 + ((size_t)prv*BB + (mrow+n))*HH + q*8;
        half8 hA[16];
        LdSC<0,16,64>::go(hA, hb);
        VDRAIN;
#pragma unroll
        for (int g = 0; g < 4; ++g)
#pragma unroll
          for (int c = 0; c < 16; ++c){
            half8 w = *(const half8*)(WSc + wrowb[g] + ((q*16 + (4+c)*64) ^ xr));
            acc[g] = __builtin_amdgcn_mfma_f32_16x16x32_f16(hA[c], w, acc[g], 0, 0, 0);
          }
      } else {
        wait_flags(F1, F2, FP, t, 0, 0, lane);
        const _Float16* hb = H1 + ((size_t)prv*BB + (mrow+n))*HH + 512 + q*8;
        half8 hA[16];
        LdSC<0,16,64>::go(hA, hb);
        VDRAIN;
#pragma unroll
        for (int g = 0; g < 4; ++g)
#pragma unroll
          for (int c = 0; c < 16; ++c){
            half8 w = *(const half8*)(WSc + wrowb[g] + ((q*16 + (20+c)*64) ^ xr));
            acc[g] = __builtin_amdgcn_mfma_f32_16x16x32_f16(hA[c], w, acc[g], 0, 0, 0);
          }
      }
      // 2-phase K-half reduction (kh=1 -> kh=0)
      if (kh){ RBv[ri] = acc[0]; RBv[ri+1] = acc[1]; }
      __syncthreads();
      if (!kh){ acc[0] += RBv[ri]; acc[1] += RBv[ri+1]; }
      __syncthreads();
      if (kh){ RBv[ri] = acc[2]; RBv[ri+1] = acc[3]; }
      __syncthreads();
      if (!kh){
        acc[2] += RBv[ri]; acc[3] += RBv[ri+1];
        _Float16* ho = H1 + (size_t)cur*BB*HH;
#pragma unroll
        for (int r = 0; r < 4; ++r){
          const int b = mrow + q*4 + r;
          float gi = acc[0][r] + bias[0];
          float gf = acc[1][r] + bias[1];
          float gg = acc[2][r] + bias[2];
          float go_ = acc[3][r] + bias[3];
          float cc = sigm(gf)*c1r[r] + sigm(gi)*tanhf(gg);
          c1r[r] = cc;
          float h = sigm(go_)*tanhf(cc);
          st_sc(ho + (size_t)b*HH + j, (_Float16)h);
        }
        asm volatile("s_waitcnt vmcnt(0)" ::: "memory");
        if (lane == 0)
          __hip_atomic_store(&F1[wg*4 + mg], (unsigned)(t+1),
                             __ATOMIC_RELAXED, __HIP_MEMORY_SCOPE_AGENT);
      }
      __syncthreads();                   // RB reusable next iteration
      prv = cur; cur = (cur == 2) ? 0 : cur + 1;
    }
  } else if (wg < 192){
    // ================= layer 2 =================
    const int j0 = (wg - 64) << 3;
    for (int idx = tid; idx < 8192; idx += 512){
      int row = idx >> 8, kc = idx & 255;
      const _Float16* src = W2 + ((size_t)((row>>3)*HH + j0 + (row&7)))*2048 + kc*8;
      *(half8*)(WSc + row*4096 + ((kc*16) ^ ((row&7)<<4))) = *(const half8*)src;
    }
    __syncthreads();

    const int jj = j0 + (n & 7);
    float bias[4];
#pragma unroll
    for (int g = 0; g < 4; ++g) bias[g] = bi2[g*HH + jj] + bh2[g*HH + jj];
    const int rbase = (n < 8) ? 0 : 2;
    const int rowb0 = (((n>>3))*8 + (n&7))*4096;       // gates i,f rows
    const int rowb1 = ((2 + (n>>3))*8 + (n&7))*4096;   // gates g,o rows
    float c2r[2] = {0.f, 0.f};
    int cur = 0, prv = 2;
#pragma unroll 1
    for (int t = 0; t < TT; ++t){
      half8 hA[32];
      if (kh == 0){
        wait_flags(F1, F2, FP, t+1, 0, t-2, lane);     // h1(t); slot safe
        const _Float16* a = H1 + ((size_t)cur*BB + (mrow+n))*HH + q*8;
        LdSC<0,32,64>::go(hA, a);
      } else {
        wait_flags(F1, F2, FP, 0, t, 0, lane);         // peers' h2(t-1)
        const _Float16* a = H2 + ((size_t)prv*BB + (mrow+n))*HH + q*8;
        LdSC<0,32,64>::go(hA, a);
      }
      VDRAIN;
      floatx4 a0 = zero4, a1 = zero4;
      const int cb = kh << 5;
#pragma unroll
      for (int c = 0; c < 32; ++c){
        half8 w0 = *(const half8*)(WSc + rowb0 + ((q*16 + (cb+c)*64) ^ xr));
        a0 = __builtin_amdgcn_mfma_f32_16x16x32_f16(hA[c], w0, a0, 0, 0, 0);
        half8 w1 = *(const half8*)(WSc + rowb1 + ((q*16 + (cb+c)*64) ^ xr));
        a1 = __builtin_amdgcn_mfma_f32_16x16x32_f16(hA[c], w1, a1, 0, 0, 0);
      }
      if (kh){ RBv[ri] = a0; RBv[ri+1] = a1; }
      __syncthreads();
      if (!kh){
        a0 += RBv[ri]; a1 += RBv[ri+1];
        // gather i,f,g,o per (b,jj): lanes n<8 hold (i,g), n>=8 hold (f,o)
        float vi[4], vf[4], vg[4], vo[4];
#pragma unroll
        for (int r = 0; r < 4; ++r){
          float p0 = a0[r], p1 = a1[r];
          float s0 = __shfl_xor(p0, 8, 64);
          float s1 = __shfl_xor(p1, 8, 64);
          vi[r] = (n < 8) ? p0 : s0;
          vf[r] = (n < 8) ? s0 : p0;
          vg[r] = (n < 8) ? p1 : s1;
          vo[r] = (n < 8) ? s1 : p1;
        }
        _Float16* ho = H2 + (size_t)cur*BB*HH;
#pragma unroll
        for (int rr = 0; rr < 2; ++rr){
          int r = rbase + rr;
          const int b = mrow + q*4 + r;
          float gi = vi[r] + bias[0];
          float gf = vf[r] + bias[1];
          float gg = vg[r] + bias[2];
          float go_ = vo[r] + bias[3];
          float cc = sigm(gf)*c2r[rr] + sigm(gi)*tanhf(gg);
          c2r[rr] = cc;
          float h = sigm(go_)*tanhf(cc);
          st_sc(ho + (size_t)b*HH + jj, (_Float16)h);
        }
        asm volatile("s_waitcnt vmcnt(0)" ::: "memory");
        if (lane == 0)
          __hip_atomic_store(&F2[(wg-64)*4 + mg], (unsigned)(t+1),
                             __ATOMIC_RELAXED, __HIP_MEMORY_SCOPE_AGENT);
      }
      __syncthreads();
      prv = cur; cur = (cur == 2) ? 0 : cur + 1;
    }
  } else {
    // ================= output projection =================
    const int j0 = (wg - 192) << 5;
    for (int idx = tid; idx < 4096; idx += 512){
      int row = idx >> 7, kc = idx & 127;
      const _Float16* src = WL + ((size_t)(j0 + row))*1024 + kc*8;
      *(half8*)(WSc + row*2048 + ((kc*16) ^ ((row&7)<<4))) = *(const half8*)src;
    }
    __syncthreads();

    float by[2];
    int rowb[2];
#pragma unroll
    for (int p = 0; p < 2; ++p){
      by[p]   = blin[j0 + p*16 + n];
      rowb[p] = (p*16 + n)*2048;
    }
    int cur = 0;
#pragma unroll 1
    for (int t = 0; t < TT; ++t){
      wait_flags(F1, F2, FP, 0, t+1, 0, lane);         // h2(t) ready
      const _Float16* a = H2 + ((size_t)cur*BB + (mrow+n))*HH + kh*512 + q*8;
      half8 hA[16];
      LdSC<0,16,64>::go(hA, a);
      VDRAIN;
      floatx4 a0 = zero4, a1 = zero4;
#pragma unroll
      for (int c = 0; c < 16; ++c){
        half8 w0 = *(const half8*)(WSc + rowb[0] + ((q*16 + (kh*16+c)*64) ^ xr));
        a0 = __builtin_amdgcn_mfma_f32_16x16x32_f16(hA[c], w0, a0, 0, 0, 0);
        half8 w1 = *(const half8*)(WSc + rowb[1] + ((q*16 + (kh*16+c)*64) ^ xr));
        a1 = __builtin_amdgcn_mfma_f32_16x16x32_f16(hA[c], w1, a1, 0, 0, 0);
      }
      if (kh){ RBv[ri] = a0; RBv[ri+1] = a1; }
      __syncthreads();
      if (!kh){
        a0 += RBv[ri]; a1 += RBv[ri+1];
#pragma unroll
        for (int r = 0; r < 4; ++r){
          int b = mrow + q*4 + r;
          out[((size_t)b*TT + t)*OO + (j0 + n)]      = a0[r] + by[0];
          out[((size_t)b*TT + t)*OO + (j0 + 16 + n)] = a1[r] + by[1];
        }
        if (lane == 0)
          __hip_atomic_store(&FP[(wg-192)*4 + mg], (unsigned)(t+1),
                             __ATOMIC_RELAXED, __HIP_MEMORY_SCOPE_AGENT);
      }
      __syncthreads();
      cur = (cur == 2) ? 0 : cur + 1;
    }
  }
}

// ---------------- launch ----------------
extern "C" void kernel_launch(void* const* d_in, const int* in_sizes, int n_in,
                              void* d_out, int out_size, void* d_ws, size_t ws_size,
                              hipStream_t stream){
  const float* x    = (const float*)d_in[0];
  const float* wih1 = (const float*)d_in[1];
  const float* whh1 = (const float*)d_in[2];
  const float* bi1  = (const float*)d_in[3];
  const float* bh1  = (const float*)d_in[4];
  const float* wih2 = (const float*)d_in[5];
  const float* whh2 = (const float*)d_in[6];
  const float* bi2  = (const float*)d_in[7];
  const float* bh2  = (const float*)d_in[8];
  const float* wlin = (const float*)d_in[9];
  const float* blin = (const float*)d_in[10];
  float* out = (float*)d_out;

  char* ws = (char*)d_ws;
  _Float16* X16 = (_Float16*)(ws + 0);          //  8,388,608  [512][64][128]
  _Float16* W1  = (_Float16*)(ws + 8388608);    //  9,437,184  [4096][1152]
  _Float16* W2  = (_Float16*)(ws + 17825792);   // 16,777,216  [4096][2048]
  _Float16* WL  = (_Float16*)(ws + 34603008);   //    262,144  [128][1024]
  _Float16* H1  = (_Float16*)(ws + 34865152);   //    393,216  [3][64][1024]
  _Float16* H2  = (_Float16*)(ws + 35258368);   //    393,216  [3][64][1024]
  unsigned int* bar = (unsigned int*)(ws + 35651584);  // 4096 B flag area
  // total 35,655,680 bytes (within round-0-proven footprint)

  prep_x_kernel<<<dim3(16384), dim3(256), 0, stream>>>(x, X16, bar);
  prep_w_kernel<<<dim3(52480), dim3(256), 0, stream>>>(wih1, whh1, wih2, whh2, wlin,
                                                       W1, W2, WL, H1, H2);
  lstm_persist<<<dim3(NWG), dim3(512), 0, stream>>>(
      X16, W1, W2, WL, H1, H2,
      bi1, bh1, bi2, bh2, blin, out, bar);
}